// Round 2
// baseline (399.334 us; speedup 1.0000x reference)
//
#include <hip/hip_runtime.h>
#include <hip/hip_bf16.h>
#include <math.h>

typedef __hip_bfloat16 bf16;
typedef __attribute__((ext_vector_type(8))) short short8;
typedef __attribute__((ext_vector_type(4))) float floatx4;

#define B_ 4
#define L_ 4096
#define D_ 512
#define N_ 64
#define M_ (B_*L_)   // 16384 rows

__device__ __forceinline__ float b2f(bf16 v){ return __bfloat162float(v); }
__device__ __forceinline__ bf16  f2b(float v){ return __float2bfloat16(v); }
__device__ __forceinline__ short f2bs(float v){ bf16 h = __float2bfloat16(v); short s; __builtin_memcpy(&s,&h,2); return s; }

// ---------------- weight transpose+downcast (K,N) f32 -> (N,K) bf16 ----------------
__global__ __launch_bounds__(1024) void k_transpose(const float* __restrict__ src,
                                                    bf16* __restrict__ dst, int K, int N){
    __shared__ float tile[32][33];
    int n0 = blockIdx.x*32, k0 = blockIdx.y*32;
    int tx = threadIdx.x, ty = threadIdx.y;
    tile[ty][tx] = src[(size_t)(k0+ty)*N + n0+tx];
    __syncthreads();
    ((short*)dst)[(size_t)(n0+ty)*K + k0+tx] = f2bs(tile[tx][ty]);
}

// ---------------- 64x64 MFMA tile core ----------------
// A: (M,K) row-major, f32 (converted at staging) or bf16.  Wt: (N,K) bf16.
// block = 256 threads = 4 waves in 2x2; each wave 32x32 via 2x2 mfma_16x16x32 tiles.
template<bool A_IS_F32>
__device__ __forceinline__ void gemm_tile_64x64(const void* __restrict__ Aptr,
                                                const bf16* __restrict__ Wt,
                                                int K, int m0, int n0,
                                                short (*As)[32], short (*Ns)[32],
                                                floatx4 acc[2][2]){
    int tid  = threadIdx.x;
    int w    = tid >> 6, lane = tid & 63;
    int wr   = w >> 1,  wc   = w & 1;
    int quad = lane >> 4, r16 = lane & 15;
    #pragma unroll
    for (int i=0;i<2;i++)
        #pragma unroll
        for (int j=0;j<2;j++)
            #pragma unroll
            for (int e=0;e<4;e++) acc[i][j][e] = 0.f;

    int lrow = tid >> 2, lkg = (tid & 3) * 8;
    for (int k0 = 0; k0 < K; k0 += 32){
        if (A_IS_F32){
            const float* ap = (const float*)Aptr + (size_t)(m0+lrow)*K + k0 + lkg;
            float4 a0 = *(const float4*)ap;
            float4 a1 = *(const float4*)(ap+4);
            short8 s;
            s[0]=f2bs(a0.x); s[1]=f2bs(a0.y); s[2]=f2bs(a0.z); s[3]=f2bs(a0.w);
            s[4]=f2bs(a1.x); s[5]=f2bs(a1.y); s[6]=f2bs(a1.z); s[7]=f2bs(a1.w);
            *(short8*)&As[lrow][lkg] = s;
        } else {
            *(short8*)&As[lrow][lkg] =
                *(const short8*)((const short*)Aptr + (size_t)(m0+lrow)*K + k0 + lkg);
        }
        *(short8*)&Ns[lrow][lkg] = *(const short8*)((const short*)Wt + (size_t)(n0+lrow)*K + k0 + lkg);
        __syncthreads();
        short8 af[2], bfr[2];
        #pragma unroll
        for (int t=0;t<2;t++) af[t]  = *(short8*)&As[wr*32 + t*16 + r16][quad*8];
        #pragma unroll
        for (int t=0;t<2;t++) bfr[t] = *(short8*)&Ns[wc*32 + t*16 + r16][quad*8];
        #pragma unroll
        for (int i=0;i<2;i++)
            #pragma unroll
            for (int j=0;j<2;j++)
                acc[i][j] = __builtin_amdgcn_mfma_f32_16x16x32_bf16(af[i], bfr[j], acc[i][j], 0,0,0);
        __syncthreads();
    }
}

// D element (i,j,reg): row = wr*32+i*16+quad*4+reg ; col = wc*32+j*16+(lane&15)

// ---------------- K1: xproj GEMM + split + silu ----------------
__global__ __launch_bounds__(256) void k_xproj(const float* __restrict__ x,
        const bf16* __restrict__ Wt, const float* __restrict__ bias,
        float* __restrict__ xbar, bf16* __restrict__ siluz){
    __shared__ short As[64][32], Ns[64][32];
    floatx4 acc[2][2];
    int m0 = blockIdx.x*64, n0 = blockIdx.y*64;
    gemm_tile_64x64<true>(x, Wt, 512, m0, n0, As, Ns, acc);
    int tid=threadIdx.x, w=tid>>6, lane=tid&63, wr=w>>1, wc=w&1, quad=lane>>4, r16=lane&15;
    #pragma unroll
    for (int i=0;i<2;i++)
    #pragma unroll
    for (int j=0;j<2;j++)
    #pragma unroll
    for (int reg=0;reg<4;reg++){
        int gr = m0 + wr*32 + i*16 + quad*4 + reg;
        int gc = n0 + wc*32 + j*16 + r16;
        float v = acc[i][j][reg] + bias[gc];
        if (gc < 512){
            xbar[(size_t)gr*512 + gc] = v;
        } else {
            float s = v / (1.f + expf(-v));           // silu(z)
            siluz[(size_t)gr*512 + (gc-512)] = f2b(s);
        }
    }
}

// ---------------- K2: B/C projection GEMM + rmsnorm over n=64 ----------------
__global__ __launch_bounds__(256) void k_bcproj(const float* __restrict__ xbar,
        const bf16* __restrict__ WtB, const bf16* __restrict__ WtC,
        const float* __restrict__ gB, const float* __restrict__ gC,
        float* __restrict__ Bm, float* __restrict__ Cm){
    __shared__ short As[64][32], Ns[64][32];
    __shared__ float Ls[64][64];
    __shared__ float rfac[64];
    const bf16* Wt = blockIdx.y ? WtC : WtB;
    const float* g = blockIdx.y ? gC  : gB;
    float* outp    = blockIdx.y ? Cm  : Bm;
    floatx4 acc[2][2];
    int m0 = blockIdx.x*64;
    gemm_tile_64x64<true>(xbar, Wt, 512, m0, 0, As, Ns, acc);
    int tid=threadIdx.x, w=tid>>6, lane=tid&63, wr=w>>1, wc=w&1, quad=lane>>4, r16=lane&15;
    #pragma unroll
    for (int i=0;i<2;i++)
    #pragma unroll
    for (int j=0;j<2;j++)
    #pragma unroll
    for (int reg=0;reg<4;reg++)
        Ls[wr*32+i*16+quad*4+reg][wc*32+j*16+r16] = acc[i][j][reg];
    __syncthreads();
    if (tid < 64){
        float ss = 0.f;
        #pragma unroll
        for (int c=0;c<64;c++){ float t = Ls[tid][c]; ss += t*t; }
        rfac[tid] = rsqrtf(ss*(1.f/64.f) + 1e-6f);
    }
    __syncthreads();
    #pragma unroll
    for (int it=0; it<16; it++){
        int idx = it*256 + tid;
        int r = idx >> 6, cc = idx & 63;
        outp[(size_t)(m0+r)*64 + cc] = Ls[r][cc] * rfac[r] * g[cc];
    }
}

// ---------------- K3: dt GEMM + softplus/clip -> log_a ----------------
__global__ __launch_bounds__(256) void k_dtproj(const float* __restrict__ xbar,
        const bf16* __restrict__ Wt, const float* __restrict__ dt_bias,
        const float* __restrict__ A_log, float* __restrict__ la){
    __shared__ short As[64][32], Ns[64][32];
    floatx4 acc[2][2];
    int m0 = blockIdx.x*64, n0 = blockIdx.y*64;
    gemm_tile_64x64<true>(xbar, Wt, 512, m0, n0, As, Ns, acc);
    int tid=threadIdx.x, w=tid>>6, lane=tid&63, wr=w>>1, wc=w&1, quad=lane>>4, r16=lane&15;
    #pragma unroll
    for (int i=0;i<2;i++)
    #pragma unroll
    for (int j=0;j<2;j++)
    #pragma unroll
    for (int reg=0;reg<4;reg++){
        int gr = m0 + wr*32 + i*16 + quad*4 + reg;
        int gc = n0 + wc*32 + j*16 + r16;
        float v  = acc[i][j][reg] + dt_bias[gc];
        float sp = (v > 15.f) ? v : log1pf(expf(v));           // softplus
        float dt = fminf(fmaxf(sp, 1e-4f), 5.f);
        float Ad = -expf(fminf(fmaxf(A_log[gc], -20.f), 2.f));
        // log_a = log(clip(exp(clip(dt*A,-20,0)),1e-8,1)) = clamp(dt*A, ln 1e-8, 0)
        float lav = fminf(fmaxf(dt*Ad, -18.420680743952367f), 0.f);
        la[(size_t)gr*512 + gc] = lav;
    }
}

// ---------------- K4: per-chunk cumsum + a_total + local chunk state ----------------
// grid (c=64, b=4), block 512 (one thread per d)
__global__ __launch_bounds__(512) void k_chunkstate(const float* __restrict__ la,
        const float* __restrict__ xbar, const float* __restrict__ Bm,
        float* __restrict__ local, float* __restrict__ atot){
    int c = blockIdx.x, b = blockIdx.y, d = threadIdx.x;
    size_t rowbase = (size_t)b*L_ + (size_t)c*64;
    float cs[64];
    float s = 0.f;
    #pragma unroll
    for (int p=0;p<64;p++){ s += la[(rowbase+p)*512 + d]; cs[p] = s; }
    float cl = cs[63];
    size_t cb = (size_t)c*4 + b;
    atot[cb*512 + d] = expf(cl);
    #pragma unroll
    for (int p=0;p<64;p++)
        cs[p] = xbar[(rowbase+p)*512 + d] * expf(cl - cs[p]);   // now w[p]
    const float* Bbase = Bm + rowbase*64;
    size_t obase = (cb*64)*512 + d;
    #pragma unroll 1
    for (int n4=0;n4<16;n4++){
        float a0=0.f,a1=0.f,a2=0.f,a3=0.f;
        #pragma unroll
        for (int p=0;p<64;p++){
            float4 bv = *(const float4*)(Bbase + (size_t)p*64 + n4*4);  // wave-uniform
            a0 += bv.x*cs[p]; a1 += bv.y*cs[p]; a2 += bv.z*cs[p]; a3 += bv.w*cs[p];
        }
        local[obase + (size_t)(n4*4+0)*512] = a0;
        local[obase + (size_t)(n4*4+1)*512] = a1;
        local[obase + (size_t)(n4*4+2)*512] = a2;
        local[obase + (size_t)(n4*4+3)*512] = a3;
    }
}

// ---------------- K5: sequential inter-chunk scan (in place: local -> chunk-entry state) --
__global__ __launch_bounds__(256) void k_scan(float* __restrict__ local,
        const float* __restrict__ atot){
    int idx = blockIdx.x*256 + threadIdx.x;      // over b*n*d = 131072
    int d = idx & 511, n = (idx >> 9) & 63, b = idx >> 15;
    float s = 0.f;
    for (int c=0;c<64;c++){
        size_t cb = (size_t)c*4 + b;
        size_t off = (cb*64 + n)*512 + d;
        float v = local[off];
        local[off] = s;                           // state entering chunk c
        s = s * atot[cb*512 + d] + v;
        if (!isfinite(s)) s = 0.f;
    }
}

// ---------------- K6: exact in-chunk recurrence -> y ----------------
// grid (c=64,b=4), block 512 (thread=d), 64 states in registers
__global__ __launch_bounds__(512) void k_intra(const float* __restrict__ la,
        const float* __restrict__ xbar, const float* __restrict__ Bm,
        const float* __restrict__ Cm, const float* __restrict__ Sprev,
        float* __restrict__ y){
    int c = blockIdx.x, b = blockIdx.y, d = threadIdx.x;
    size_t cb = (size_t)c*4 + b;
    float st[64];
    #pragma unroll
    for (int n=0;n<64;n++) st[n] = Sprev[(cb*64 + n)*512 + d];
    size_t rowbase = (size_t)b*L_ + (size_t)c*64;
    #pragma unroll 1
    for (int i=0;i<64;i++){
        size_t row = rowbase + i;
        float ai = expf(la[row*512 + d]);
        float xi = xbar[row*512 + d];
        const float* Br = Bm + row*64;            // wave-uniform rows
        const float* Cr = Cm + row*64;
        float yv = 0.f;
        #pragma unroll
        for (int n4=0;n4<16;n4++){
            float4 bv = *(const float4*)(Br + n4*4);
            float4 cv = *(const float4*)(Cr + n4*4);
            st[n4*4+0] = ai*st[n4*4+0] + bv.x*xi;  yv += cv.x*st[n4*4+0];
            st[n4*4+1] = ai*st[n4*4+1] + bv.y*xi;  yv += cv.y*st[n4*4+1];
            st[n4*4+2] = ai*st[n4*4+2] + bv.z*xi;  yv += cv.z*st[n4*4+2];
            st[n4*4+3] = ai*st[n4*4+3] + bv.w*xi;  yv += cv.w*st[n4*4+3];
        }
        if (!isfinite(yv)) yv = 0.f;
        y[row*512 + d] = yv;
    }
}

// ---------------- K7: +D_skip*xbar, rmsnorm(d=512), *silu(z) -> u (bf16) ----------------
__global__ __launch_bounds__(256) void k_outnorm(const float* __restrict__ y,
        const float* __restrict__ xbar, const float* __restrict__ Dskip,
        const float* __restrict__ g, const bf16* __restrict__ siluz,
        bf16* __restrict__ u){
    int wave = threadIdx.x >> 6, lane = threadIdx.x & 63;
    size_t row = (size_t)blockIdx.x*4 + wave;
    float v[8]; float ss = 0.f;
    #pragma unroll
    for (int j=0;j<8;j++){
        int d = j*64 + lane;
        float t = y[row*512 + d] + Dskip[d] * xbar[row*512 + d];
        v[j] = t; ss += t*t;
    }
    #pragma unroll
    for (int m=1;m<64;m<<=1) ss += __shfl_xor(ss, m, 64);
    float r = rsqrtf(ss*(1.f/512.f) + 1e-6f);
    #pragma unroll
    for (int j=0;j<8;j++){
        int d = j*64 + lane;
        u[row*512 + d] = f2b(v[j] * r * g[d] * b2f(siluz[row*512 + d]));
    }
}

// ---------------- K8: final GEMM u@W_out + b_out -> out (f32) ----------------
__global__ __launch_bounds__(256) void k_outproj(const bf16* __restrict__ u,
        const bf16* __restrict__ Wt, const float* __restrict__ bias,
        float* __restrict__ out){
    __shared__ short As[64][32], Ns[64][32];
    floatx4 acc[2][2];
    int m0 = blockIdx.x*64, n0 = blockIdx.y*64;
    gemm_tile_64x64<false>(u, Wt, 512, m0, n0, As, Ns, acc);
    int tid=threadIdx.x, w=tid>>6, lane=tid&63, wr=w>>1, wc=w&1, quad=lane>>4, r16=lane&15;
    #pragma unroll
    for (int i=0;i<2;i++)
    #pragma unroll
    for (int j=0;j<2;j++)
    #pragma unroll
    for (int reg=0;reg<4;reg++){
        int gr = m0 + wr*32 + i*16 + quad*4 + reg;
        int gc = n0 + wc*32 + j*16 + r16;
        out[(size_t)gr*512 + gc] = acc[i][j][reg] + bias[gc];
    }
}

extern "C" void kernel_launch(void* const* d_in, const int* in_sizes, int n_in,
                              void* d_out, int out_size, void* d_ws, size_t ws_size,
                              hipStream_t stream){
    const float* x       = (const float*)d_in[0];
    const float* A_log   = (const float*)d_in[1];
    const float* dt_bias = (const float*)d_in[2];
    const float* D_skip  = (const float*)d_in[3];
    const float* W_xproj = (const float*)d_in[4];
    const float* b_xproj = (const float*)d_in[5];
    const float* W_B     = (const float*)d_in[6];
    const float* W_C     = (const float*)d_in[7];
    const float* W_dt    = (const float*)d_in[8];
    const float* g_B     = (const float*)d_in[9];
    const float* g_C     = (const float*)d_in[10];
    const float* g_out   = (const float*)d_in[11];
    const float* W_out   = (const float*)d_in[12];
    const float* b_out   = (const float*)d_in[13];
    float* out = (float*)d_out;

    char* wp = (char*)d_ws;
    auto alloc = [&](size_t bytes)->char*{ char* p = wp; wp += (bytes + 255) & ~(size_t)255; return p; };
    float* xbar  = (float*)alloc((size_t)M_*512*4);
    bf16*  siluz = (bf16*) alloc((size_t)M_*512*2);
    float* la    = (float*)alloc((size_t)M_*512*4);
    float* Bm    = (float*)alloc((size_t)M_*64*4);
    float* Cm    = (float*)alloc((size_t)M_*64*4);
    float* local = (float*)alloc((size_t)256*64*512*4);   // (c,b,n,d); becomes Sprev after k_scan
    float* atot  = (float*)alloc((size_t)256*512*4);
    float* ybuf  = (float*)alloc((size_t)M_*512*4);
    bf16*  u     = (bf16*) alloc((size_t)M_*512*2);
    bf16*  WtX   = (bf16*) alloc((size_t)1024*512*2);
    bf16*  WtD   = (bf16*) alloc((size_t)512*512*2);
    bf16*  WtO   = (bf16*) alloc((size_t)512*512*2);
    bf16*  WtB   = (bf16*) alloc((size_t)64*512*2);
    bf16*  WtC   = (bf16*) alloc((size_t)64*512*2);

    dim3 tb(32,32);
    k_transpose<<<dim3(32,16), tb, 0, stream>>>(W_xproj, WtX, 512, 1024);
    k_transpose<<<dim3(16,16), tb, 0, stream>>>(W_dt,   WtD, 512, 512);
    k_transpose<<<dim3(16,16), tb, 0, stream>>>(W_out,  WtO, 512, 512);
    k_transpose<<<dim3(2,16),  tb, 0, stream>>>(W_B,    WtB, 512, 64);
    k_transpose<<<dim3(2,16),  tb, 0, stream>>>(W_C,    WtC, 512, 64);

    k_xproj     <<<dim3(M_/64, 16), 256, 0, stream>>>(x, WtX, b_xproj, xbar, siluz);
    k_bcproj    <<<dim3(M_/64, 2),  256, 0, stream>>>(xbar, WtB, WtC, g_B, g_C, Bm, Cm);
    k_dtproj    <<<dim3(M_/64, 8),  256, 0, stream>>>(xbar, WtD, dt_bias, A_log, la);
    k_chunkstate<<<dim3(64, 4),     512, 0, stream>>>(la, xbar, Bm, local, atot);
    k_scan      <<<512,             256, 0, stream>>>(local, atot);
    k_intra     <<<dim3(64, 4),     512, 0, stream>>>(la, xbar, Bm, Cm, local, ybuf);
    k_outnorm   <<<M_/4,            256, 0, stream>>>(ybuf, xbar, D_skip, g_out, siluz, u);
    k_outproj   <<<dim3(M_/64, 8),  256, 0, stream>>>(u, WtO, b_out, out);
}